// Round 1
// baseline (181.918 us; speedup 1.0000x reference)
//
#include <hip/hip_runtime.h>
#include <math.h>

#define NCLS 5
#define NB 32
#define NBOX 20
#define FEPS 1e-7f
#define DENSE_ITER 8

// Per-scale loss accumulators in workspace.
struct Acc {
    double coord[3];
    double obj[3];
    double noobj[3];   // dense softplus sum; sparse winners subtract occupied cells
    double cls[3];
    int    npos[3];
    int    pad;
};

__device__ __forceinline__ float softplus_f(float x) {
    // logaddexp(x, 0) = max(x,0) + log1p(exp(-|x|))  (matches jax.nn.softplus)
    return log1pf(expf(-fabsf(x))) + fmaxf(x, 0.0f);
}

// ---------------------------------------------------------------------------
// Sparse kernel: one thread per (scale, batch, box). Resolves scatter
// collisions in-register (last-write-wins == highest box index, matching
// sequential scatter-set semantics). Winners compute coord/obj/cls terms and
// subtract their softplus(obj) from the dense noobj sum.
// ---------------------------------------------------------------------------
__global__ void yolo_sparse_kernel(const float* __restrict__ pred0,
                                   const float* __restrict__ pred1,
                                   const float* __restrict__ pred2,
                                   const float* __restrict__ targets,
                                   const float* __restrict__ anchors,
                                   Acc* __restrict__ acc) {
    int t = blockIdx.x * blockDim.x + threadIdx.x;
    if (t >= 3 * NB * NBOX) return;
    int s = t / (NB * NBOX);
    int r = t % (NB * NBOX);
    int b = r / NBOX;
    int n = r % NBOX;

    int W  = (s == 0) ? 100 : (s == 1) ? 50 : 25;
    int HW = W * W;
    const float* pred = (s == 0) ? pred0 : (s == 1) ? pred1 : pred2;

    const float* tp = targets + (size_t)(b * NBOX + n) * 5;
    float tx = tp[0], ty = tp[1], tw = tp[2], th = tp[3];
    int  tcls = (int)tp[4];

    float fW = (float)W;
    int gx = (int)floorf(tx * fW);
    int gy = (int)floorf(ty * fW);
    if (gx < 0 || gx >= W || gy < 0 || gy >= W) return;  // invalid -> dropped

    // Last-write-wins: if any later valid box maps to the same cell, we lose.
    for (int m = n + 1; m < NBOX; ++m) {
        const float* tq = targets + (size_t)(b * NBOX + m) * 5;
        int gxm = (int)floorf(tq[0] * fW);
        int gym = (int)floorf(tq[1] * fW);
        if (gxm == gx && gym == gy &&
            gxm >= 0 && gxm < W && gym >= 0 && gym < W) return;
    }

    // Winner: gather the 10 channels of anchor 0 at this cell.
    const float* base = pred + (size_t)(b * 30) * HW + (size_t)gy * W + gx;
    float p0 = base[0 * (size_t)HW];
    float p1 = base[1 * (size_t)HW];
    float p2 = base[2 * (size_t)HW];
    float p3 = base[3 * (size_t)HW];
    float p4 = base[4 * (size_t)HW];
    float l0 = base[5 * (size_t)HW];
    float l1 = base[6 * (size_t)HW];
    float l2 = base[7 * (size_t)HW];
    float l3 = base[8 * (size_t)HW];
    float l4 = base[9 * (size_t)HW];

    float aw = anchors[s * 6 + 0];
    float ah = anchors[s * 6 + 1];

    float px = (1.0f / (1.0f + expf(-p0)) + (float)gx) / fW;
    float py = (1.0f / (1.0f + expf(-p1)) + (float)gy) / fW;
    float pw = expf(p2) * aw / 800.0f;
    float ph = expf(p3) * ah / 800.0f;

    // CIoU (direct port of the reference arithmetic, f32)
    float b1x1 = px - pw * 0.5f, b1y1 = py - ph * 0.5f;
    float b1x2 = px + pw * 0.5f, b1y2 = py + ph * 0.5f;
    float b2x1 = tx - tw * 0.5f, b2y1 = ty - th * 0.5f;
    float b2x2 = tx + tw * 0.5f, b2y2 = ty + th * 0.5f;
    float iw = fmaxf(fminf(b1x2, b2x2) - fmaxf(b1x1, b2x1), 0.0f);
    float ih = fmaxf(fminf(b1y2, b2y2) - fmaxf(b1y1, b2y1), 0.0f);
    float inter = iw * ih;
    float uni   = pw * ph + tw * th - inter;
    float iou   = inter / (uni + FEPS);
    float ex = fmaxf(b1x2, b2x2) - fminf(b1x1, b2x1);
    float ey = fmaxf(b1y2, b2y2) - fminf(b1y1, b2y1);
    float cd = (px - tx) * (px - tx) + (py - ty) * (py - ty);
    float diou = iou - cd / (ex * ex + ey * ey + FEPS);
    float dv = atanf(tw / (th + FEPS)) - atanf(pw / (ph + FEPS));
    float v  = (float)(4.0 / (M_PI * M_PI)) * dv * dv;
    float alpha = v / (1.0f - iou + v + FEPS);
    float ciou  = diou - alpha * v;

    // class NLL (log_softmax with max-shift)
    float mx  = fmaxf(fmaxf(fmaxf(l0, l1), fmaxf(l2, l3)), l4);
    float lse = logf(expf(l0 - mx) + expf(l1 - mx) + expf(l2 - mx) +
                     expf(l3 - mx) + expf(l4 - mx));
    float lt  = (tcls == 0) ? l0 : (tcls == 1) ? l1 : (tcls == 2) ? l2
              : (tcls == 3) ? l3 : l4;
    float nll = -(lt - mx - lse);

    atomicAdd(&acc->coord[s], (double)(1.0f - ciou));
    atomicAdd(&acc->obj[s],   (double)softplus_f(-p4));
    atomicAdd(&acc->noobj[s], -(double)softplus_f(p4));
    atomicAdd(&acc->cls[s],   (double)nll);
    atomicAdd(&acc->npos[s],  1);
}

// ---------------------------------------------------------------------------
// Dense kernel: sum softplus over the 3 objectness channels of every scale.
// Elements enumerate (scale, plane=b*3+a, pos in HW); channel = a*10+4.
// ---------------------------------------------------------------------------
template <int HW>
__device__ __forceinline__ double dense_elem(const float* __restrict__ pred, int e) {
    int plane = e / HW;          // b*3 + a
    int pos   = e % HW;
    int b = plane / 3;
    int a = plane % 3;
    float v = pred[(size_t)(b * 30 + a * 10 + 4) * HW + pos];
    return (double)softplus_f(v);
}

__global__ void yolo_dense_kernel(const float* __restrict__ pred0,
                                  const float* __restrict__ pred1,
                                  const float* __restrict__ pred2,
                                  Acc* __restrict__ acc) {
    const int N0 = 32 * 3 * 10000;          // 960000
    const int N1 = 32 * 3 * 2500;           // 240000
    const int N2 = 32 * 3 * 625;            // 60000
    const int NT = N0 + N1 + N2;            // 1260000

    double s0 = 0.0, s1 = 0.0, s2 = 0.0;
    int base = blockIdx.x * (blockDim.x * DENSE_ITER) + threadIdx.x;
#pragma unroll
    for (int i = 0; i < DENSE_ITER; ++i) {
        int e = base + i * blockDim.x;
        if (e >= NT) break;
        if (e < N0) {
            s0 += dense_elem<10000>(pred0, e);
        } else if (e < N0 + N1) {
            s1 += dense_elem<2500>(pred1, e - N0);
        } else {
            s2 += dense_elem<625>(pred2, e - N0 - N1);
        }
    }

    // wave reduction (64 lanes)
#pragma unroll
    for (int off = 32; off > 0; off >>= 1) {
        s0 += __shfl_down(s0, off);
        s1 += __shfl_down(s1, off);
        s2 += __shfl_down(s2, off);
    }
    __shared__ double lds[4][3];
    int wave = threadIdx.x >> 6;
    int lane = threadIdx.x & 63;
    if (lane == 0) { lds[wave][0] = s0; lds[wave][1] = s1; lds[wave][2] = s2; }
    __syncthreads();
    if (threadIdx.x == 0) {
        double t0 = 0.0, t1 = 0.0, t2 = 0.0;
        int nwaves = (blockDim.x + 63) >> 6;
        for (int w = 0; w < nwaves; ++w) {
            t0 += lds[w][0]; t1 += lds[w][1]; t2 += lds[w][2];
        }
        if (t0 != 0.0) atomicAdd(&acc->noobj[0], t0);
        if (t1 != 0.0) atomicAdd(&acc->noobj[1], t1);
        if (t2 != 0.0) atomicAdd(&acc->noobj[2], t2);
    }
}

// ---------------------------------------------------------------------------
// Finalize: combine per-scale sums into the 5 outputs.
// ---------------------------------------------------------------------------
__global__ void yolo_finalize_kernel(const Acc* __restrict__ acc,
                                     float* __restrict__ out) {
    if (threadIdx.x != 0 || blockIdx.x != 0) return;
    const double cnt_all[3] = {960000.0, 240000.0, 60000.0};
    double tc = 0.0, to = 0.0, tn = 0.0, tk = 0.0;
    for (int s = 0; s < 3; ++s) {
        double np   = (double)acc->npos[s];
        bool   has  = np > 0.0;
        double safe = fmax(np, 1.0);
        double c = has ? acc->coord[s] / safe : 0.0;
        double o = has ? acc->obj[s]   / safe : 0.0;
        double k = has ? acc->cls[s]   / safe : 0.0;
        double nn = acc->noobj[s] / (cnt_all[s] - np);
        tc += c;          // COORD_S = 1
        to += o;          // OBJ_S   = 1
        tn += 0.5 * nn;   // NOOBJ_S = 0.5
        tk += k;          // CLS_S   = 1
    }
    double tot = tc + to + tn + tk;
    out[0] = (float)tot;
    out[1] = (float)tc;
    out[2] = (float)to;
    out[3] = (float)tn;
    out[4] = (float)tk;
}

extern "C" void kernel_launch(void* const* d_in, const int* in_sizes, int n_in,
                              void* d_out, int out_size, void* d_ws, size_t ws_size,
                              hipStream_t stream) {
    const float* pred0   = (const float*)d_in[0];
    const float* pred1   = (const float*)d_in[1];
    const float* pred2   = (const float*)d_in[2];
    const float* targets = (const float*)d_in[3];
    const float* anchors = (const float*)d_in[4];
    float* out = (float*)d_out;
    Acc* acc = (Acc*)d_ws;

    hipMemsetAsync(acc, 0, sizeof(Acc), stream);

    const int n_sparse = 3 * NB * NBOX;   // 1920
    yolo_sparse_kernel<<<(n_sparse + 255) / 256, 256, 0, stream>>>(
        pred0, pred1, pred2, targets, anchors, acc);

    const int NT = 1260000;
    const int per_block = 256 * DENSE_ITER;
    yolo_dense_kernel<<<(NT + per_block - 1) / per_block, 256, 0, stream>>>(
        pred0, pred1, pred2, acc);

    yolo_finalize_kernel<<<1, 64, 0, stream>>>(acc, out);
}

// Round 2
// 109.259 us; speedup vs baseline: 1.6650x; 1.6650x over previous
//
#include <hip/hip_runtime.h>
#include <math.h>

#define NCLS 5
#define NB 32
#define NBOX 20
#define FEPS 1e-7f

// Dense block partition (256 threads each):
//   [0,192)    scale0 objectness, float4   (240000 vec4)
//   [192,240)  scale1 objectness, float4   (60000 vec4)
//   [240,264)  scale2 objectness, scalar   (60000 floats)
//   [264,267)  sparse role, one block per scale
#define DB0 192
#define DB1 48
#define DB2 24
#define NDENSE (DB0 + DB1 + DB2)
#define NBLOCKS (NDENSE + 3)

struct Ws {
    double coord[3];
    double obj[3];
    double noobj_sub[3];  // softplus(obj) at occupied anchor-0 cells (to subtract)
    double cls[3];
    int    npos[3];
    int    pad;
    double partial[NDENSE];  // dense per-block noobj partial sums
};

__device__ __forceinline__ float softplus_f(float x) {
    // jax.nn.softplus = max(x,0) + log1p(exp(-|x|))
    return log1pf(expf(-fabsf(x))) + fmaxf(x, 0.0f);
}

// Block-wide reduction over 256 threads (4 waves). Result valid on thread 0.
__device__ double block_reduce_d(double v) {
#pragma unroll
    for (int off = 32; off > 0; off >>= 1) v += __shfl_down(v, off);
    __shared__ double lds[4];
    int wave = threadIdx.x >> 6;
    int lane = threadIdx.x & 63;
    __syncthreads();  // protect LDS reuse across successive calls
    if (lane == 0) lds[wave] = v;
    __syncthreads();
    double r = 0.0;
    if (threadIdx.x == 0) {
        r = lds[0] + lds[1] + lds[2] + lds[3];
    }
    return r;
}

__device__ __forceinline__ double dense_f4_sum(const float4* __restrict__ p,
                                               int nvec, int planevec,
                                               int idx0, int stride) {
    // planes enumerate (b*3 + a); channel = a*10 + 4; plane vec base = c*planevec
    double s = 0.0;
    for (int i = idx0; i < nvec; i += stride) {
        int plane = i / planevec;
        int pos   = i - plane * planevec;
        int b = plane / 3;
        int a = plane - b * 3;
        float4 v = p[(size_t)(b * 30 + a * 10 + 4) * planevec + pos];
        s += (double)(softplus_f(v.x) + softplus_f(v.y) +
                      softplus_f(v.z) + softplus_f(v.w));
    }
    return s;
}

__global__ __launch_bounds__(256) void yolo_main(const float* __restrict__ pred0,
                                                 const float* __restrict__ pred1,
                                                 const float* __restrict__ pred2,
                                                 const float* __restrict__ targets,
                                                 const float* __restrict__ anchors,
                                                 Ws* __restrict__ ws) {
    const int blk = blockIdx.x;
    const int tid = threadIdx.x;

    if (blk < NDENSE) {
        // ---------------- dense noobj softplus sums ----------------
        double s = 0.0;
        if (blk < DB0) {
            s = dense_f4_sum((const float4*)pred0, 240000, 2500,
                             blk * 256 + tid, DB0 * 256);
        } else if (blk < DB0 + DB1) {
            s = dense_f4_sum((const float4*)pred1, 60000, 625,
                             (blk - DB0) * 256 + tid, DB1 * 256);
        } else {
            // scale2 scalar: HW=625, 96 planes, 60000 elements
            int idx0   = (blk - DB0 - DB1) * 256 + tid;
            int stride = DB2 * 256;
            for (int i = idx0; i < 60000; i += stride) {
                int plane = i / 625;
                int pos   = i - plane * 625;
                int b = plane / 3;
                int a = plane - b * 3;
                s += (double)softplus_f(pred2[(size_t)(b * 30 + a * 10 + 4) * 625 + pos]);
            }
        }
        double r = block_reduce_d(s);
        if (tid == 0) ws->partial[blk] = r;
        return;
    }

    // ---------------- sparse role: one block per scale ----------------
    const int s = blk - NDENSE;
    const int W  = (s == 0) ? 100 : (s == 1) ? 50 : 25;
    const int HW = W * W;
    const float fW = (float)W;
    const float* pred = (s == 0) ? pred0 : (s == 1) ? pred1 : pred2;

    // Stage all targets in LDS: 32*20*5 = 3200 floats (12.8 KB)
    __shared__ float tl[NB * NBOX * 5];
    for (int i = tid; i < NB * NBOX * 5; i += 256) tl[i] = targets[i];
    __syncthreads();

    const float aw = anchors[s * 6 + 0];
    const float ah = anchors[s * 6 + 1];

    double a_coord = 0.0, a_obj = 0.0, a_nsub = 0.0, a_cls = 0.0;
    int a_npos = 0;

#pragma unroll
    for (int it = 0; it < 3; ++it) {
        int item = tid + it * 256;
        if (item >= NB * NBOX) break;
        int b = item / NBOX;
        int n = item - b * NBOX;

        const float* tp = &tl[(b * NBOX + n) * 5];
        float tx = tp[0], ty = tp[1], tw = tp[2], th = tp[3];
        int  tcls = (int)tp[4];

        int gx = (int)floorf(tx * fW);
        int gy = (int)floorf(ty * fW);
        if (gx < 0 || gx >= W || gy < 0 || gy >= W) continue;

        // last-write-wins collision resolution
        bool win = true;
        for (int m = n + 1; m < NBOX; ++m) {
            const float* tq = &tl[(b * NBOX + m) * 5];
            int gxm = (int)floorf(tq[0] * fW);
            int gym = (int)floorf(tq[1] * fW);
            if (gxm == gx && gym == gy && gxm >= 0 && gxm < W && gym >= 0 && gym < W) {
                win = false;
                break;
            }
        }
        if (!win) continue;

        const float* base = pred + (size_t)(b * 30) * HW + (size_t)gy * W + gx;
        float p0 = base[0 * (size_t)HW];
        float p1 = base[1 * (size_t)HW];
        float p2 = base[2 * (size_t)HW];
        float p3 = base[3 * (size_t)HW];
        float p4 = base[4 * (size_t)HW];
        float l0 = base[5 * (size_t)HW];
        float l1 = base[6 * (size_t)HW];
        float l2 = base[7 * (size_t)HW];
        float l3 = base[8 * (size_t)HW];
        float l4 = base[9 * (size_t)HW];

        float px = (1.0f / (1.0f + expf(-p0)) + (float)gx) / fW;
        float py = (1.0f / (1.0f + expf(-p1)) + (float)gy) / fW;
        float pw = expf(p2) * aw / 800.0f;
        float ph = expf(p3) * ah / 800.0f;

        float b1x1 = px - pw * 0.5f, b1y1 = py - ph * 0.5f;
        float b1x2 = px + pw * 0.5f, b1y2 = py + ph * 0.5f;
        float b2x1 = tx - tw * 0.5f, b2y1 = ty - th * 0.5f;
        float b2x2 = tx + tw * 0.5f, b2y2 = ty + th * 0.5f;
        float iw = fmaxf(fminf(b1x2, b2x2) - fmaxf(b1x1, b2x1), 0.0f);
        float ih = fmaxf(fminf(b1y2, b2y2) - fmaxf(b1y1, b2y1), 0.0f);
        float inter = iw * ih;
        float uni   = pw * ph + tw * th - inter;
        float iou   = inter / (uni + FEPS);
        float ex = fmaxf(b1x2, b2x2) - fminf(b1x1, b2x1);
        float ey = fmaxf(b1y2, b2y2) - fminf(b1y1, b2y1);
        float cd = (px - tx) * (px - tx) + (py - ty) * (py - ty);
        float diou = iou - cd / (ex * ex + ey * ey + FEPS);
        float dv = atanf(tw / (th + FEPS)) - atanf(pw / (ph + FEPS));
        float v  = (float)(4.0 / (M_PI * M_PI)) * dv * dv;
        float alpha = v / (1.0f - iou + v + FEPS);
        float ciou  = diou - alpha * v;

        float mx  = fmaxf(fmaxf(fmaxf(l0, l1), fmaxf(l2, l3)), l4);
        float lse = logf(expf(l0 - mx) + expf(l1 - mx) + expf(l2 - mx) +
                         expf(l3 - mx) + expf(l4 - mx));
        float lt  = (tcls == 0) ? l0 : (tcls == 1) ? l1 : (tcls == 2) ? l2
                  : (tcls == 3) ? l3 : l4;
        float nll = -(lt - mx - lse);

        a_coord += (double)(1.0f - ciou);
        a_obj   += (double)softplus_f(-p4);
        a_nsub  += (double)softplus_f(p4);
        a_cls   += (double)nll;
        a_npos  += 1;
    }

    double rc = block_reduce_d(a_coord);
    double ro = block_reduce_d(a_obj);
    double rn = block_reduce_d(a_nsub);
    double rk = block_reduce_d(a_cls);
    double rp = block_reduce_d((double)a_npos);
    if (tid == 0) {
        ws->coord[s]     = rc;
        ws->obj[s]       = ro;
        ws->noobj_sub[s] = rn;
        ws->cls[s]       = rk;
        ws->npos[s]      = (int)(rp + 0.5);
    }
}

__global__ __launch_bounds__(256) void yolo_finalize(const Ws* __restrict__ ws,
                                                     float* __restrict__ out) {
    const int tid = threadIdx.x;
    // parallel partial sums per scale segment
    double v0 = 0.0, v1 = 0.0, v2 = 0.0;
    for (int i = tid; i < DB0; i += 256) v0 += ws->partial[i];
    for (int i = tid; i < DB1; i += 256) v1 += ws->partial[DB0 + i];
    for (int i = tid; i < DB2; i += 256) v2 += ws->partial[DB0 + DB1 + i];
    double n0 = block_reduce_d(v0);
    double n1 = block_reduce_d(v1);
    double n2 = block_reduce_d(v2);

    if (tid == 0) {
        const double dense_n[3] = {n0, n1, n2};
        const double cnt_all[3] = {960000.0, 240000.0, 60000.0};
        double tc = 0.0, to = 0.0, tn = 0.0, tk = 0.0;
        for (int s = 0; s < 3; ++s) {
            double np   = (double)ws->npos[s];
            bool   has  = np > 0.0;
            double safe = fmax(np, 1.0);
            tc += has ? ws->coord[s] / safe : 0.0;
            to += has ? ws->obj[s]   / safe : 0.0;
            tk += has ? ws->cls[s]   / safe : 0.0;
            double nsum = dense_n[s] - ws->noobj_sub[s];
            tn += 0.5 * (nsum / (cnt_all[s] - np));
        }
        double tot = tc + to + tn + tk;
        out[0] = (float)tot;
        out[1] = (float)tc;
        out[2] = (float)to;
        out[3] = (float)tn;
        out[4] = (float)tk;
    }
}

extern "C" void kernel_launch(void* const* d_in, const int* in_sizes, int n_in,
                              void* d_out, int out_size, void* d_ws, size_t ws_size,
                              hipStream_t stream) {
    const float* pred0   = (const float*)d_in[0];
    const float* pred1   = (const float*)d_in[1];
    const float* pred2   = (const float*)d_in[2];
    const float* targets = (const float*)d_in[3];
    const float* anchors = (const float*)d_in[4];
    float* out = (float*)d_out;
    Ws* ws = (Ws*)d_ws;

    yolo_main<<<NBLOCKS, 256, 0, stream>>>(pred0, pred1, pred2, targets, anchors, ws);
    yolo_finalize<<<1, 256, 0, stream>>>(ws, out);
}

// Round 3
// 100.965 us; speedup vs baseline: 1.8018x; 1.0822x over previous
//
#include <hip/hip_runtime.h>
#include <math.h>

#define NB 32
#define NBOX 20
#define FEPS 1e-7f

// Dense block partition (256 threads each, grid-stride within segment):
//   [0,DB0)            scale0 objectness, float4   (240000 vec4)
//   [DB0,DB0+DB1)      scale1 objectness, float4   (60000 vec4)
//   [DB0+DB1,NDENSE)   scale2 objectness, scalar   (60000 floats)
//   [NDENSE,NDENSE+9)  sparse role: 3 blocks per scale, <=214 items each
#define DB0 576
#define DB1 144
#define DB2 72
#define NDENSE (DB0 + DB1 + DB2)        // 792
#define SP_PER 3                        // sparse blocks per scale
#define NBLOCKS (NDENSE + 3 * SP_PER)   // 801
#define ITEMS_PER_SP 214                // ceil(32*20 / 3)

struct Ws {
    double sp[3][SP_PER][5];    // [scale][part][{coord, obj, noobj_sub, cls, npos}]
    double partial[NDENSE];     // dense per-block noobj partial sums
};

__device__ __forceinline__ float softplus_f(float x) {
    // jax.nn.softplus = max(x,0) + log1p(exp(-|x|))
    return log1pf(expf(-fabsf(x))) + fmaxf(x, 0.0f);
}

// Block-wide reduction over 256 threads (4 waves). Result valid on thread 0.
__device__ double block_reduce_d(double v) {
#pragma unroll
    for (int off = 32; off > 0; off >>= 1) v += __shfl_down(v, off);
    __shared__ double lds[4];
    int wave = threadIdx.x >> 6;
    int lane = threadIdx.x & 63;
    __syncthreads();  // protect LDS reuse across successive calls
    if (lane == 0) lds[wave] = v;
    __syncthreads();
    double r = 0.0;
    if (threadIdx.x == 0) r = lds[0] + lds[1] + lds[2] + lds[3];
    return r;
}

__device__ __forceinline__ double dense_f4_sum(const float4* __restrict__ p,
                                               int nvec, int planevec,
                                               int idx0, int stride) {
    // planes enumerate (b*3 + a); channel = a*10 + 4
    double s = 0.0;
    for (int i = idx0; i < nvec; i += stride) {
        int plane = i / planevec;
        int pos   = i - plane * planevec;
        int b = plane / 3;
        int a = plane - b * 3;
        float4 v = p[(size_t)(b * 30 + a * 10 + 4) * planevec + pos];
        s += (double)(softplus_f(v.x) + softplus_f(v.y) +
                      softplus_f(v.z) + softplus_f(v.w));
    }
    return s;
}

__global__ __launch_bounds__(256) void yolo_main(const float* __restrict__ pred0,
                                                 const float* __restrict__ pred1,
                                                 const float* __restrict__ pred2,
                                                 const float* __restrict__ targets,
                                                 const float* __restrict__ anchors,
                                                 Ws* __restrict__ ws) {
    const int blk = blockIdx.x;
    const int tid = threadIdx.x;

    if (blk < NDENSE) {
        // ---------------- dense noobj softplus sums ----------------
        double s = 0.0;
        if (blk < DB0) {
            s = dense_f4_sum((const float4*)pred0, 240000, 2500,
                             blk * 256 + tid, DB0 * 256);
        } else if (blk < DB0 + DB1) {
            s = dense_f4_sum((const float4*)pred1, 60000, 625,
                             (blk - DB0) * 256 + tid, DB1 * 256);
        } else {
            // scale2 scalar: HW=625, 96 planes, 60000 elements
            int idx0   = (blk - DB0 - DB1) * 256 + tid;
            int stride = DB2 * 256;
            for (int i = idx0; i < 60000; i += stride) {
                int plane = i / 625;
                int pos   = i - plane * 625;
                int b = plane / 3;
                int a = plane - b * 3;
                s += (double)softplus_f(pred2[(size_t)(b * 30 + a * 10 + 4) * 625 + pos]);
            }
        }
        double r = block_reduce_d(s);
        if (tid == 0) ws->partial[blk] = r;
        return;
    }

    // ---------------- sparse role: 3 blocks per scale, 1 item/thread ----------
    const int q    = blk - NDENSE;
    const int s    = q / SP_PER;
    const int part = q - s * SP_PER;
    const int W  = (s == 0) ? 100 : (s == 1) ? 50 : 25;
    const int HW = W * W;
    const float fW = (float)W;
    const float* pred = (s == 0) ? pred0 : (s == 1) ? pred1 : pred2;

    // Stage all targets in LDS: 32*20*5 = 3200 floats (12.8 KB)
    __shared__ float tl[NB * NBOX * 5];
    for (int i = tid; i < NB * NBOX * 5; i += 256) tl[i] = targets[i];
    __syncthreads();

    const float aw = anchors[s * 6 + 0];
    const float ah = anchors[s * 6 + 1];

    double a_coord = 0.0, a_obj = 0.0, a_nsub = 0.0, a_cls = 0.0, a_npos = 0.0;

    const int item = part * ITEMS_PER_SP + tid;
    if (tid < ITEMS_PER_SP && item < NB * NBOX) {
        const int b = item / NBOX;
        const int n = item - b * NBOX;

        const float* tp = &tl[item * 5];
        float tx = tp[0], ty = tp[1], tw = tp[2], th = tp[3];
        int  tcls = (int)tp[4];

        int gx = (int)floorf(tx * fW);
        int gy = (int)floorf(ty * fW);
        bool valid = (gx >= 0 && gx < W && gy >= 0 && gy < W);

        // last-write-wins collision resolution (vs later boxes in same batch)
        bool win = valid;
        if (valid) {
            for (int m = n + 1; m < NBOX; ++m) {
                const float* tq = &tl[(b * NBOX + m) * 5];
                int gxm = (int)floorf(tq[0] * fW);
                int gym = (int)floorf(tq[1] * fW);
                if (gxm == gx && gym == gy &&
                    gxm >= 0 && gxm < W && gym >= 0 && gym < W) {
                    win = false;
                    break;
                }
            }
        }

        if (win) {
            const float* base = pred + (size_t)(b * 30) * HW + (size_t)gy * W + gx;
            float p0 = base[0 * (size_t)HW];
            float p1 = base[1 * (size_t)HW];
            float p2 = base[2 * (size_t)HW];
            float p3 = base[3 * (size_t)HW];
            float p4 = base[4 * (size_t)HW];
            float l0 = base[5 * (size_t)HW];
            float l1 = base[6 * (size_t)HW];
            float l2 = base[7 * (size_t)HW];
            float l3 = base[8 * (size_t)HW];
            float l4 = base[9 * (size_t)HW];

            float px = (1.0f / (1.0f + expf(-p0)) + (float)gx) / fW;
            float py = (1.0f / (1.0f + expf(-p1)) + (float)gy) / fW;
            float pw = expf(p2) * aw / 800.0f;
            float ph = expf(p3) * ah / 800.0f;

            float b1x1 = px - pw * 0.5f, b1y1 = py - ph * 0.5f;
            float b1x2 = px + pw * 0.5f, b1y2 = py + ph * 0.5f;
            float b2x1 = tx - tw * 0.5f, b2y1 = ty - th * 0.5f;
            float b2x2 = tx + tw * 0.5f, b2y2 = ty + th * 0.5f;
            float iw = fmaxf(fminf(b1x2, b2x2) - fmaxf(b1x1, b2x1), 0.0f);
            float ih = fmaxf(fminf(b1y2, b2y2) - fmaxf(b1y1, b2y1), 0.0f);
            float inter = iw * ih;
            float uni   = pw * ph + tw * th - inter;
            float iou   = inter / (uni + FEPS);
            float ex = fmaxf(b1x2, b2x2) - fminf(b1x1, b2x1);
            float ey = fmaxf(b1y2, b2y2) - fminf(b1y1, b2y1);
            float cd = (px - tx) * (px - tx) + (py - ty) * (py - ty);
            float diou = iou - cd / (ex * ex + ey * ey + FEPS);
            float dv = atanf(tw / (th + FEPS)) - atanf(pw / (ph + FEPS));
            float v  = (float)(4.0 / (M_PI * M_PI)) * dv * dv;
            float alpha = v / (1.0f - iou + v + FEPS);
            float ciou  = diou - alpha * v;

            float mx  = fmaxf(fmaxf(fmaxf(l0, l1), fmaxf(l2, l3)), l4);
            float lse = logf(expf(l0 - mx) + expf(l1 - mx) + expf(l2 - mx) +
                             expf(l3 - mx) + expf(l4 - mx));
            float lt  = (tcls == 0) ? l0 : (tcls == 1) ? l1 : (tcls == 2) ? l2
                      : (tcls == 3) ? l3 : l4;
            float nll = -(lt - mx - lse);

            a_coord = (double)(1.0f - ciou);
            a_obj   = (double)softplus_f(-p4);
            a_nsub  = (double)softplus_f(p4);
            a_cls   = (double)nll;
            a_npos  = 1.0;
        }
    }

    double rc = block_reduce_d(a_coord);
    double ro = block_reduce_d(a_obj);
    double rn = block_reduce_d(a_nsub);
    double rk = block_reduce_d(a_cls);
    double rp = block_reduce_d(a_npos);
    if (tid == 0) {
        ws->sp[s][part][0] = rc;
        ws->sp[s][part][1] = ro;
        ws->sp[s][part][2] = rn;
        ws->sp[s][part][3] = rk;
        ws->sp[s][part][4] = rp;
    }
}

__global__ __launch_bounds__(256) void yolo_finalize(const Ws* __restrict__ ws,
                                                     float* __restrict__ out) {
    const int tid = threadIdx.x;
    // parallel partial sums per scale segment
    double v0 = 0.0, v1 = 0.0, v2 = 0.0;
    for (int i = tid; i < DB0; i += 256) v0 += ws->partial[i];
    for (int i = tid; i < DB1; i += 256) v1 += ws->partial[DB0 + i];
    for (int i = tid; i < DB2; i += 256) v2 += ws->partial[DB0 + DB1 + i];
    double n0 = block_reduce_d(v0);
    double n1 = block_reduce_d(v1);
    double n2 = block_reduce_d(v2);

    if (tid == 0) {
        const double dense_n[3] = {n0, n1, n2};
        const double cnt_all[3] = {960000.0, 240000.0, 60000.0};
        double tc = 0.0, to = 0.0, tn = 0.0, tk = 0.0;
        for (int s = 0; s < 3; ++s) {
            double csum = 0.0, osum = 0.0, nsub = 0.0, ksum = 0.0, np = 0.0;
            for (int p = 0; p < SP_PER; ++p) {
                csum += ws->sp[s][p][0];
                osum += ws->sp[s][p][1];
                nsub += ws->sp[s][p][2];
                ksum += ws->sp[s][p][3];
                np   += ws->sp[s][p][4];
            }
            bool   has  = np > 0.0;
            double safe = fmax(np, 1.0);
            tc += has ? csum / safe : 0.0;
            to += has ? osum / safe : 0.0;
            tk += has ? ksum / safe : 0.0;
            tn += 0.5 * ((dense_n[s] - nsub) / (cnt_all[s] - np));
        }
        double tot = tc + to + tn + tk;
        out[0] = (float)tot;
        out[1] = (float)tc;
        out[2] = (float)to;
        out[3] = (float)tn;
        out[4] = (float)tk;
    }
}

extern "C" void kernel_launch(void* const* d_in, const int* in_sizes, int n_in,
                              void* d_out, int out_size, void* d_ws, size_t ws_size,
                              hipStream_t stream) {
    const float* pred0   = (const float*)d_in[0];
    const float* pred1   = (const float*)d_in[1];
    const float* pred2   = (const float*)d_in[2];
    const float* targets = (const float*)d_in[3];
    const float* anchors = (const float*)d_in[4];
    float* out = (float*)d_out;
    Ws* ws = (Ws*)d_ws;

    yolo_main<<<NBLOCKS, 256, 0, stream>>>(pred0, pred1, pred2, targets, anchors, ws);
    yolo_finalize<<<1, 256, 0, stream>>>(ws, out);
}